// Round 1
// baseline (840.390 us; speedup 1.0000x reference)
//
#include <hip/hip_runtime.h>
#include <math.h>

#define NPTS 2048
#define NB 2
#define NC 128
#define NH 128
#define INV_TEMP 10.0f
#define NITERS 20
#define EPSF 1e-8f

static __device__ __forceinline__ void lse_merge(float& m, float& s, float m2, float s2){
  float M = fmaxf(m, m2);
  s = s * expf(m - M) + s2 * expf(m2 - M);
  m = M;
}

// ---------------- dustbin head: Conv1d(C->H) -> ReLU -> Conv1d(H->1) ----------------
__global__ __launch_bounds__(128) void dust_kernel(
    const float* __restrict__ fd, const float* __restrict__ fs,
    const float* __restrict__ W1, const float* __restrict__ b1,
    const float* __restrict__ W2, const float* __restrict__ b2,
    float* __restrict__ dust_d, float* __restrict__ dust_s){
  const int chunk = blockIdx.x, b = blockIdx.y, view = blockIdx.z;
  const float* x = (view == 0 ? fd : fs) + (size_t)b * NC * NPTS;
  float* out = (view == 0 ? dust_d : dust_s) + (size_t)b * NPTS;
  const int n0 = chunk * 16;
  __shared__ float xs[NC][17];
  __shared__ float red[NH][17];
  const int j = threadIdx.x; // hidden unit / channel loader
  #pragma unroll
  for (int p = 0; p < 16; ++p) xs[j][p] = x[(size_t)j * NPTS + n0 + p];
  __syncthreads();
  float acc[16];
  float bb = b1[j];
  #pragma unroll
  for (int p = 0; p < 16; ++p) acc[p] = bb;
  for (int c = 0; c < NC; ++c){
    float w = W1[j * NC + c];
    #pragma unroll
    for (int p = 0; p < 16; ++p) acc[p] = fmaf(w, xs[c][p], acc[p]);
  }
  float w2 = W2[j];
  #pragma unroll
  for (int p = 0; p < 16; ++p) red[j][p] = w2 * fmaxf(acc[p], 0.0f);
  __syncthreads();
  for (int s = NH / 2; s >= 1; s >>= 1){
    if (j < s){
      #pragma unroll
      for (int p = 0; p < 16; ++p) red[j][p] += red[j + s][p];
    }
    __syncthreads();
  }
  if (j < 16) out[n0 + j] = red[0][j] + b2[0];
}

// ---------------- S = feat_d^T feat_s / TEMP, plus transposed copy ----------------
#define GP 68
__global__ __launch_bounds__(256) void gemm_kernel(
    const float* __restrict__ fd, const float* __restrict__ fs,
    float* __restrict__ S, float* __restrict__ ST){
  const int cb = blockIdx.x, rb = blockIdx.y, b = blockIdx.z;
  const float* A = fd + (size_t)b * NC * NPTS;
  const float* Bm = fs + (size_t)b * NC * NPTS;
  __shared__ float Als[NC * GP];
  __shared__ float Bls[NC * GP];
  const int tid = threadIdx.x;
  for (int idx = tid; idx < NC * 64; idx += 256){
    int ch = idx >> 6, i = idx & 63;
    Als[ch * GP + i] = A[(size_t)ch * NPTS + rb * 64 + i];
    Bls[ch * GP + i] = Bm[(size_t)ch * NPTS + cb * 64 + i];
  }
  __syncthreads();
  const int tx = tid & 15, ty = tid >> 4;
  float acc[4][4] = {};
  for (int c = 0; c < NC; ++c){
    float4 a4 = *(const float4*)&Als[c * GP + ty * 4];
    float4 b4 = *(const float4*)&Bls[c * GP + tx * 4];
    float av[4] = {a4.x, a4.y, a4.z, a4.w};
    float bv[4] = {b4.x, b4.y, b4.z, b4.w};
    #pragma unroll
    for (int i = 0; i < 4; ++i)
      #pragma unroll
      for (int jj = 0; jj < 4; ++jj)
        acc[i][jj] = fmaf(av[i], bv[jj], acc[i][jj]);
  }
  float* Sb = S + (size_t)b * NPTS * NPTS;
  float* STb = ST + (size_t)b * NPTS * NPTS;
  const int r0 = rb * 64 + ty * 4, c0 = cb * 64 + tx * 4;
  #pragma unroll
  for (int i = 0; i < 4; ++i){
    float4 v = make_float4(acc[i][0]*INV_TEMP, acc[i][1]*INV_TEMP, acc[i][2]*INV_TEMP, acc[i][3]*INV_TEMP);
    *(float4*)&Sb[(size_t)(r0 + i) * NPTS + c0] = v;
  }
  #pragma unroll
  for (int jj = 0; jj < 4; ++jj){
    float4 v = make_float4(acc[0][jj]*INV_TEMP, acc[1][jj]*INV_TEMP, acc[2][jj]*INV_TEMP, acc[3][jj]*INV_TEMP);
    *(float4*)&STb[(size_t)(c0 + jj) * NPTS + r0] = v;
  }
}

// ---------------- one Sinkhorn half-step (mode 0: row norms; mode 1: col norms) ----------------
// mode 0 (phase A): u_ds[r] = -lse_c(S[r,c]  + v_ds[c])   (r==N: dust_d row)
//                   u_sd[r] = -lse_c(ST[r,c] + v_sd[c])   (r==N: dust_s row)
// mode 1 (phase B): v_sd[r] = -lse( lse_c(S[r,c]  + u_sd[c]), dust_s[r] + u_sd[N] )
//                   v_ds[r] = -lse( lse_c(ST[r,c] + u_ds[c]), dust_d[r] + u_ds[N] )
__global__ __launch_bounds__(256) void phase_kernel(
    const float* __restrict__ S, const float* __restrict__ ST,
    const float* __restrict__ dust_d, const float* __restrict__ dust_s,
    float* __restrict__ u_ds, float* __restrict__ u_sd,
    float* __restrict__ v_ds, float* __restrict__ v_sd,
    const int mode){
  const int r = blockIdx.x, b = blockIdx.y, mat = blockIdx.z;
  const int tid = threadIdx.x;
  const float* row;
  const float* off;
  if (mode == 0){
    if (mat == 0){
      row = (r < NPTS) ? (S + ((size_t)b * NPTS + r) * NPTS) : (dust_d + (size_t)b * NPTS);
      off = v_ds + (size_t)b * NPTS;
    } else {
      row = (r < NPTS) ? (ST + ((size_t)b * NPTS + r) * NPTS) : (dust_s + (size_t)b * NPTS);
      off = v_sd + (size_t)b * NPTS;
    }
  } else {
    if (mat == 0){
      row = S + ((size_t)b * NPTS + r) * NPTS;
      off = u_sd + (size_t)b * (NPTS + 1);
    } else {
      row = ST + ((size_t)b * NPTS + r) * NPTS;
      off = u_ds + (size_t)b * (NPTS + 1);
    }
  }
  float4 r0 = *(const float4*)&row[tid * 4];
  float4 r1 = *(const float4*)&row[tid * 4 + 1024];
  float4 o0 = *(const float4*)&off[tid * 4];
  float4 o1 = *(const float4*)&off[tid * 4 + 1024];
  float x[8] = {r0.x+o0.x, r0.y+o0.y, r0.z+o0.z, r0.w+o0.w,
                r1.x+o1.x, r1.y+o1.y, r1.z+o1.z, r1.w+o1.w};
  float m = x[0];
  #pragma unroll
  for (int i = 1; i < 8; ++i) m = fmaxf(m, x[i]);
  float s = 0.f;
  #pragma unroll
  for (int i = 0; i < 8; ++i) s += expf(x[i] - m);
  #pragma unroll
  for (int d = 1; d < 64; d <<= 1){
    float m2 = __shfl_xor(m, d);
    float s2 = __shfl_xor(s, d);
    lse_merge(m, s, m2, s2);
  }
  __shared__ float sm[4], ssum[4];
  const int w = tid >> 6;
  if ((tid & 63) == 0){ sm[w] = m; ssum[w] = s; }
  __syncthreads();
  if (tid == 0){
    float M = sm[0], Sv = ssum[0];
    #pragma unroll
    for (int i = 1; i < 4; ++i) lse_merge(M, Sv, sm[i], ssum[i]);
    float lse = M + logf(Sv);
    if (mode == 0){
      if (mat == 0) u_ds[(size_t)b * (NPTS + 1) + r] = -lse;
      else          u_sd[(size_t)b * (NPTS + 1) + r] = -lse;
    } else {
      float dsc, uN;
      if (mat == 0){ dsc = dust_s[(size_t)b * NPTS + r]; uN = u_sd[(size_t)b * (NPTS + 1) + NPTS]; }
      else         { dsc = dust_d[(size_t)b * NPTS + r]; uN = u_ds[(size_t)b * (NPTS + 1) + NPTS]; }
      float e = dsc + uN;
      float M2 = fmaxf(lse, e);
      lse = M2 + logf(expf(lse - M2) + expf(e - M2));
      if (mat == 0) v_sd[(size_t)b * NPTS + r] = -lse;
      else          v_ds[(size_t)b * NPTS + r] = -lse;
    }
  }
}

// ---------------- final losses: one scan over S ----------------
__global__ __launch_bounds__(256) void loss_kernel(
    const float* __restrict__ S,
    const float* __restrict__ u_ds, const float* __restrict__ u_sd,
    const float* __restrict__ v_ds, const float* __restrict__ v_sd,
    float* __restrict__ part){
  const int r = blockIdx.x, b = blockIdx.y;
  const int tid = threadIdx.x;
  const float* row = S + ((size_t)b * NPTS + r) * NPTS;
  const float uds = u_ds[(size_t)b * (NPTS + 1) + r];
  const float vsd = v_sd[(size_t)b * NPTS + r];
  const float* vds = v_ds + (size_t)b * NPTS;
  const float* usd = u_sd + (size_t)b * (NPTS + 1);
  float sd = 0.f, e1 = 0.f, e2 = 0.f;
  #pragma unroll
  for (int k = 0; k < 2; ++k){
    const int c = tid * 4 + k * 1024;
    float4 sv = *(const float4*)&row[c];
    float4 a = *(const float4*)&vds[c];
    float4 q = *(const float4*)&usd[c];
    float svv[4] = {sv.x, sv.y, sv.z, sv.w};
    float av[4] = {a.x, a.y, a.z, a.w};
    float qv[4] = {q.x, q.y, q.z, q.w};
    #pragma unroll
    for (int i = 0; i < 4; ++i){
      float t1 = expf(svv[i] + uds + av[i]);   // T_ds[r][c]
      float t2 = expf(svv[i] + qv[i] + vsd);   // T_sd^T[r][c]
      float d = t1 - t2;
      sd += d * d;
      e1 += t1 * logf(t1 + EPSF);
      e2 += t2 * logf(t2 + EPSF);
    }
  }
  #pragma unroll
  for (int d = 1; d < 64; d <<= 1){
    sd += __shfl_xor(sd, d);
    e1 += __shfl_xor(e1, d);
    e2 += __shfl_xor(e2, d);
  }
  __shared__ float rs[4][3];
  const int w = tid >> 6;
  if ((tid & 63) == 0){ rs[w][0] = sd; rs[w][1] = e1; rs[w][2] = e2; }
  __syncthreads();
  if (tid == 0){
    float a0 = rs[0][0] + rs[1][0] + rs[2][0] + rs[3][0];
    float a1 = rs[0][1] + rs[1][1] + rs[2][1] + rs[3][1];
    float a2 = rs[0][2] + rs[1][2] + rs[2][2] + rs[3][2];
    float* p = part + ((size_t)b * NPTS + r) * 4;
    p[0] = a0; p[1] = a1; p[2] = a2;
  }
}

__global__ __launch_bounds__(256) void final_kernel(const float* __restrict__ part, float* __restrict__ out){
  const int tid = threadIdx.x;
  float s0 = 0.f, s1 = 0.f, s2 = 0.f;
  for (int i = tid; i < NB * NPTS; i += 256){
    s0 += part[(size_t)i * 4 + 0];
    s1 += part[(size_t)i * 4 + 1];
    s2 += part[(size_t)i * 4 + 2];
  }
  #pragma unroll
  for (int d = 1; d < 64; d <<= 1){
    s0 += __shfl_xor(s0, d);
    s1 += __shfl_xor(s1, d);
    s2 += __shfl_xor(s2, d);
  }
  __shared__ float rs[4][3];
  const int w = tid >> 6;
  if ((tid & 63) == 0){ rs[w][0] = s0; rs[w][1] = s1; rs[w][2] = s2; }
  __syncthreads();
  if (tid == 0){
    float a0 = rs[0][0] + rs[1][0] + rs[2][0] + rs[3][0];
    float a1 = rs[0][1] + rs[1][1] + rs[2][1] + rs[3][1];
    float a2 = rs[0][2] + rs[1][2] + rs[2][2] + rs[3][2];
    float lc = a0 / (float)((size_t)NB * NPTS * NPTS);
    float le = -0.5f * (a1 + a2) / (float)NB;
    out[0] = lc + 0.01f * le;
  }
}

extern "C" void kernel_launch(void* const* d_in, const int* in_sizes, int n_in,
                              void* d_out, int out_size, void* d_ws, size_t ws_size,
                              hipStream_t stream){
  const float* fd = (const float*)d_in[0];
  const float* fs = (const float*)d_in[1];
  const float* W1 = (const float*)d_in[2];
  const float* b1 = (const float*)d_in[3];
  const float* W2 = (const float*)d_in[4];
  const float* b2 = (const float*)d_in[5];
  float* ws = (float*)d_ws;
  float* S      = ws;
  float* ST     = S + (size_t)NB * NPTS * NPTS;
  float* dust_d = ST + (size_t)NB * NPTS * NPTS;
  float* dust_s = dust_d + (size_t)NB * NPTS;
  float* u_ds   = dust_s + (size_t)NB * NPTS;
  float* u_sd   = u_ds + (size_t)NB * (NPTS + 1);
  float* v_ds   = u_sd + (size_t)NB * (NPTS + 1);
  float* v_sd   = v_ds + (size_t)NB * NPTS;
  float* part   = v_sd + (size_t)NB * NPTS;

  // v_ds and v_sd are adjacent: zero both in one memset (initial potentials = 0)
  hipMemsetAsync(v_ds, 0, sizeof(float) * (size_t)NB * NPTS * 2, stream);

  dust_kernel<<<dim3(NPTS / 16, NB, 2), 128, 0, stream>>>(fd, fs, W1, b1, W2, b2, dust_d, dust_s);
  gemm_kernel<<<dim3(NPTS / 64, NPTS / 64, NB), 256, 0, stream>>>(fd, fs, S, ST);
  for (int it = 0; it < NITERS; ++it){
    phase_kernel<<<dim3(NPTS + 1, NB, 2), 256, 0, stream>>>(S, ST, dust_d, dust_s, u_ds, u_sd, v_ds, v_sd, 0);
    phase_kernel<<<dim3(NPTS, NB, 2), 256, 0, stream>>>(S, ST, dust_d, dust_s, u_ds, u_sd, v_ds, v_sd, 1);
  }
  loss_kernel<<<dim3(NPTS, NB), 256, 0, stream>>>(S, u_ds, u_sd, v_ds, v_sd, part);
  final_kernel<<<1, 256, 0, stream>>>(part, (float*)d_out);
}

// Round 2
// 559.008 us; speedup vs baseline: 1.5034x; 1.5034x over previous
//
#include <hip/hip_runtime.h>
#include <math.h>

#define NPTS 2048
#define NB 2
#define NC 128
#define NH 128
#define INV_TEMP 10.0f
#define NITERS 20
#define EPSF 1e-8f

static __device__ __forceinline__ void lse_merge(float& m, float& s, float m2, float s2){
  float M = fmaxf(m, m2);
  s = s * __expf(m - M) + s2 * __expf(m2 - M);
  m = M;
}

// ---------------- dustbin head: Conv1d(C->H) -> ReLU -> Conv1d(H->1) ----------------
__global__ __launch_bounds__(128) void dust_kernel(
    const float* __restrict__ fd, const float* __restrict__ fs,
    const float* __restrict__ W1, const float* __restrict__ b1,
    const float* __restrict__ W2, const float* __restrict__ b2,
    float* __restrict__ dust_d, float* __restrict__ dust_s){
  const int chunk = blockIdx.x, b = blockIdx.y, view = blockIdx.z;
  const float* x = (view == 0 ? fd : fs) + (size_t)b * NC * NPTS;
  float* out = (view == 0 ? dust_d : dust_s) + (size_t)b * NPTS;
  const int n0 = chunk * 16;
  __shared__ float xs[NC][17];
  __shared__ float red[NH][17];
  const int j = threadIdx.x;
  #pragma unroll
  for (int p = 0; p < 16; ++p) xs[j][p] = x[(size_t)j * NPTS + n0 + p];
  __syncthreads();
  float acc[16];
  float bb = b1[j];
  #pragma unroll
  for (int p = 0; p < 16; ++p) acc[p] = bb;
  for (int c = 0; c < NC; ++c){
    float w = W1[j * NC + c];
    #pragma unroll
    for (int p = 0; p < 16; ++p) acc[p] = fmaf(w, xs[c][p], acc[p]);
  }
  float w2 = W2[j];
  #pragma unroll
  for (int p = 0; p < 16; ++p) red[j][p] = w2 * fmaxf(acc[p], 0.0f);
  __syncthreads();
  for (int s = NH / 2; s >= 1; s >>= 1){
    if (j < s){
      #pragma unroll
      for (int p = 0; p < 16; ++p) red[j][p] += red[j + s][p];
    }
    __syncthreads();
  }
  if (j < 16) out[n0 + j] = red[0][j] + b2[0];
}

// ---------------- S = feat_d^T feat_s / TEMP, plus transposed copy ----------------
#define GP 68
__global__ __launch_bounds__(256) void gemm_kernel(
    const float* __restrict__ fd, const float* __restrict__ fs,
    float* __restrict__ S, float* __restrict__ ST){
  const int cb = blockIdx.x, rb = blockIdx.y, b = blockIdx.z;
  const float* A = fd + (size_t)b * NC * NPTS;
  const float* Bm = fs + (size_t)b * NC * NPTS;
  __shared__ float Als[NC * GP];
  __shared__ float Bls[NC * GP];
  const int tid = threadIdx.x;
  for (int idx = tid; idx < NC * 64; idx += 256){
    int ch = idx >> 6, i = idx & 63;
    Als[ch * GP + i] = A[(size_t)ch * NPTS + rb * 64 + i];
    Bls[ch * GP + i] = Bm[(size_t)ch * NPTS + cb * 64 + i];
  }
  __syncthreads();
  const int tx = tid & 15, ty = tid >> 4;
  float acc[4][4] = {};
  for (int c = 0; c < NC; ++c){
    float4 a4 = *(const float4*)&Als[c * GP + ty * 4];
    float4 b4 = *(const float4*)&Bls[c * GP + tx * 4];
    float av[4] = {a4.x, a4.y, a4.z, a4.w};
    float bv[4] = {b4.x, b4.y, b4.z, b4.w};
    #pragma unroll
    for (int i = 0; i < 4; ++i)
      #pragma unroll
      for (int jj = 0; jj < 4; ++jj)
        acc[i][jj] = fmaf(av[i], bv[jj], acc[i][jj]);
  }
  float* Sb = S + (size_t)b * NPTS * NPTS;
  float* STb = ST + (size_t)b * NPTS * NPTS;
  const int r0 = rb * 64 + ty * 4, c0 = cb * 64 + tx * 4;
  #pragma unroll
  for (int i = 0; i < 4; ++i){
    float4 v = make_float4(acc[i][0]*INV_TEMP, acc[i][1]*INV_TEMP, acc[i][2]*INV_TEMP, acc[i][3]*INV_TEMP);
    *(float4*)&Sb[(size_t)(r0 + i) * NPTS + c0] = v;
  }
  #pragma unroll
  for (int jj = 0; jj < 4; ++jj){
    float4 v = make_float4(acc[0][jj]*INV_TEMP, acc[1][jj]*INV_TEMP, acc[2][jj]*INV_TEMP, acc[3][jj]*INV_TEMP);
    *(float4*)&STb[(size_t)(c0 + jj) * NPTS + r0] = v;
  }
}

// ---------------- one Sinkhorn half-step: wave-per-row, shuffle-only reduction ----------------
// mode 0 (row norms): u_ds[r] = -lse_c(S[r,c]  + v_ds[c])   (r==N: dust_d row)
//                     u_sd[r] = -lse_c(ST[r,c] + v_sd[c])   (r==N: dust_s row)
// mode 1 (col norms): v_sd[r] = -lse( lse_c(S[r,c]  + u_sd[c]), dust_s[r] + u_sd[N] )
//                     v_ds[r] = -lse( lse_c(ST[r,c] + u_ds[c]), dust_d[r] + u_ds[N] )
__global__ __launch_bounds__(256) void phase_kernel(
    const float* __restrict__ S, const float* __restrict__ ST,
    const float* __restrict__ dust_d, const float* __restrict__ dust_s,
    float* __restrict__ u_ds, float* __restrict__ u_sd,
    float* __restrict__ v_ds, float* __restrict__ v_sd,
    const int mode){
  const int b = blockIdx.y, mat = blockIdx.z;
  const int w = threadIdx.x >> 6, lane = threadIdx.x & 63;
  const int r = blockIdx.x * 4 + w;
  const int rmax = (mode == 0) ? (NPTS + 1) : NPTS;
  if (r >= rmax) return;

  const float* row;
  const float* off;
  if (mode == 0){
    if (mat == 0){
      row = (r < NPTS) ? (S + ((size_t)b * NPTS + r) * NPTS) : (dust_d + (size_t)b * NPTS);
      off = v_ds + (size_t)b * NPTS;
    } else {
      row = (r < NPTS) ? (ST + ((size_t)b * NPTS + r) * NPTS) : (dust_s + (size_t)b * NPTS);
      off = v_sd + (size_t)b * NPTS;
    }
  } else {
    if (mat == 0){
      row = S + ((size_t)b * NPTS + r) * NPTS;
      off = u_sd + (size_t)b * (NPTS + 1);
    } else {
      row = ST + ((size_t)b * NPTS + r) * NPTS;
      off = u_ds + (size_t)b * (NPTS + 1);
    }
  }

  // 8 independent float4 loads per lane from the row, plus the (L1-hot) offsets vector
  float4 rv[8], ov[8];
  #pragma unroll
  for (int k = 0; k < 8; ++k){
    const int c = (k * 64 + lane) * 4;
    rv[k] = *(const float4*)&row[c];
    ov[k] = *(const float4*)&off[c];
  }
  float x[32];
  #pragma unroll
  for (int k = 0; k < 8; ++k){
    x[k*4+0] = rv[k].x + ov[k].x;
    x[k*4+1] = rv[k].y + ov[k].y;
    x[k*4+2] = rv[k].z + ov[k].z;
    x[k*4+3] = rv[k].w + ov[k].w;
  }
  float m = x[0];
  #pragma unroll
  for (int i = 1; i < 32; ++i) m = fmaxf(m, x[i]);
  float s = 0.f;
  #pragma unroll
  for (int i = 0; i < 32; ++i) s += __expf(x[i] - m);
  #pragma unroll
  for (int d = 1; d < 64; d <<= 1){
    float m2 = __shfl_xor(m, d);
    float s2 = __shfl_xor(s, d);
    lse_merge(m, s, m2, s2);
  }
  if (lane == 0){
    float lse = m + __logf(s);
    if (mode == 0){
      if (mat == 0) u_ds[(size_t)b * (NPTS + 1) + r] = -lse;
      else          u_sd[(size_t)b * (NPTS + 1) + r] = -lse;
    } else {
      float dsc, uN;
      if (mat == 0){ dsc = dust_s[(size_t)b * NPTS + r]; uN = u_sd[(size_t)b * (NPTS + 1) + NPTS]; }
      else         { dsc = dust_d[(size_t)b * NPTS + r]; uN = u_ds[(size_t)b * (NPTS + 1) + NPTS]; }
      float e = dsc + uN;
      float M2 = fmaxf(lse, e);
      lse = M2 + __logf(__expf(lse - M2) + __expf(e - M2));
      if (mat == 0) v_sd[(size_t)b * NPTS + r] = -lse;
      else          v_ds[(size_t)b * NPTS + r] = -lse;
    }
  }
}

// ---------------- final losses: wave-per-row scan over S ----------------
__global__ __launch_bounds__(256) void loss_kernel(
    const float* __restrict__ S,
    const float* __restrict__ u_ds, const float* __restrict__ u_sd,
    const float* __restrict__ v_ds, const float* __restrict__ v_sd,
    float* __restrict__ part){
  const int b = blockIdx.y;
  const int w = threadIdx.x >> 6, lane = threadIdx.x & 63;
  const int r = blockIdx.x * 4 + w;
  const float* row = S + ((size_t)b * NPTS + r) * NPTS;
  const float uds = u_ds[(size_t)b * (NPTS + 1) + r];
  const float vsd = v_sd[(size_t)b * NPTS + r];
  const float* vds = v_ds + (size_t)b * NPTS;
  const float* usd = u_sd + (size_t)b * (NPTS + 1);
  float sd = 0.f, e1 = 0.f, e2 = 0.f;
  #pragma unroll
  for (int k = 0; k < 8; ++k){
    const int c = (k * 64 + lane) * 4;
    float4 sv = *(const float4*)&row[c];
    float4 a = *(const float4*)&vds[c];
    float4 q = *(const float4*)&usd[c];
    float svv[4] = {sv.x, sv.y, sv.z, sv.w};
    float av[4] = {a.x, a.y, a.z, a.w};
    float qv[4] = {q.x, q.y, q.z, q.w};
    #pragma unroll
    for (int i = 0; i < 4; ++i){
      float t1 = __expf(svv[i] + uds + av[i]);   // T_ds[r][c]
      float t2 = __expf(svv[i] + qv[i] + vsd);   // T_sd^T[r][c]
      float d = t1 - t2;
      sd += d * d;
      e1 += t1 * __logf(t1 + EPSF);
      e2 += t2 * __logf(t2 + EPSF);
    }
  }
  #pragma unroll
  for (int d = 1; d < 64; d <<= 1){
    sd += __shfl_xor(sd, d);
    e1 += __shfl_xor(e1, d);
    e2 += __shfl_xor(e2, d);
  }
  if (lane == 0){
    float* p = part + ((size_t)b * NPTS + r) * 4;
    p[0] = sd; p[1] = e1; p[2] = e2;
  }
}

__global__ __launch_bounds__(256) void final_kernel(const float* __restrict__ part, float* __restrict__ out){
  const int tid = threadIdx.x;
  float s0 = 0.f, s1 = 0.f, s2 = 0.f;
  for (int i = tid; i < NB * NPTS; i += 256){
    s0 += part[(size_t)i * 4 + 0];
    s1 += part[(size_t)i * 4 + 1];
    s2 += part[(size_t)i * 4 + 2];
  }
  #pragma unroll
  for (int d = 1; d < 64; d <<= 1){
    s0 += __shfl_xor(s0, d);
    s1 += __shfl_xor(s1, d);
    s2 += __shfl_xor(s2, d);
  }
  __shared__ float rs[4][3];
  const int w = tid >> 6;
  if ((tid & 63) == 0){ rs[w][0] = s0; rs[w][1] = s1; rs[w][2] = s2; }
  __syncthreads();
  if (tid == 0){
    float a0 = rs[0][0] + rs[1][0] + rs[2][0] + rs[3][0];
    float a1 = rs[0][1] + rs[1][1] + rs[2][1] + rs[3][1];
    float a2 = rs[0][2] + rs[1][2] + rs[2][2] + rs[3][2];
    float lc = a0 / (float)((size_t)NB * NPTS * NPTS);
    float le = -0.5f * (a1 + a2) / (float)NB;
    out[0] = lc + 0.01f * le;
  }
}

extern "C" void kernel_launch(void* const* d_in, const int* in_sizes, int n_in,
                              void* d_out, int out_size, void* d_ws, size_t ws_size,
                              hipStream_t stream){
  const float* fd = (const float*)d_in[0];
  const float* fs = (const float*)d_in[1];
  const float* W1 = (const float*)d_in[2];
  const float* b1 = (const float*)d_in[3];
  const float* W2 = (const float*)d_in[4];
  const float* b2 = (const float*)d_in[5];
  float* ws = (float*)d_ws;
  float* S      = ws;
  float* ST     = S + (size_t)NB * NPTS * NPTS;
  float* dust_d = ST + (size_t)NB * NPTS * NPTS;
  float* dust_s = dust_d + (size_t)NB * NPTS;
  float* u_ds   = dust_s + (size_t)NB * NPTS;
  float* u_sd   = u_ds + (size_t)NB * (NPTS + 1);
  float* v_ds   = u_sd + (size_t)NB * (NPTS + 1);
  float* v_sd   = v_ds + (size_t)NB * NPTS;
  float* part   = v_sd + (size_t)NB * NPTS;

  // v_ds and v_sd are adjacent: zero both in one memset (initial potentials = 0)
  hipMemsetAsync(v_ds, 0, sizeof(float) * (size_t)NB * NPTS * 2, stream);

  dust_kernel<<<dim3(NPTS / 16, NB, 2), 128, 0, stream>>>(fd, fs, W1, b1, W2, b2, dust_d, dust_s);
  gemm_kernel<<<dim3(NPTS / 64, NPTS / 64, NB), 256, 0, stream>>>(fd, fs, S, ST);
  for (int it = 0; it < NITERS; ++it){
    phase_kernel<<<dim3((NPTS + 1 + 3) / 4, NB, 2), 256, 0, stream>>>(S, ST, dust_d, dust_s, u_ds, u_sd, v_ds, v_sd, 0);
    phase_kernel<<<dim3(NPTS / 4, NB, 2), 256, 0, stream>>>(S, ST, dust_d, dust_s, u_ds, u_sd, v_ds, v_sd, 1);
  }
  loss_kernel<<<dim3(NPTS / 4, NB), 256, 0, stream>>>(S, u_ds, u_sd, v_ds, v_sd, part);
  final_kernel<<<1, 256, 0, stream>>>(part, (float*)d_out);
}

// Round 3
// 421.749 us; speedup vs baseline: 1.9926x; 1.3255x over previous
//
#include <hip/hip_runtime.h>
#include <hip/hip_fp16.h>
#include <math.h>

#define NPTS 2048
#define NB 2
#define NC 128
#define NH 128
#define INV_TEMP 10.0f
#define NITERS 20
#define EPSF 1e-8f

static __device__ __forceinline__ void lse_merge(float& m, float& s, float m2, float s2){
  float M = fmaxf(m, m2);
  s = s * __expf(m - M) + s2 * __expf(m2 - M);
  m = M;
}

// ---------------- dustbin head: Conv1d(C->H) -> ReLU -> Conv1d(H->1) ----------------
__global__ __launch_bounds__(128) void dust_kernel(
    const float* __restrict__ fd, const float* __restrict__ fs,
    const float* __restrict__ W1, const float* __restrict__ b1,
    const float* __restrict__ W2, const float* __restrict__ b2,
    float* __restrict__ dust_d, float* __restrict__ dust_s){
  const int chunk = blockIdx.x, b = blockIdx.y, view = blockIdx.z;
  const float* x = (view == 0 ? fd : fs) + (size_t)b * NC * NPTS;
  float* out = (view == 0 ? dust_d : dust_s) + (size_t)b * NPTS;
  const int n0 = chunk * 16;
  __shared__ float xs[NC][17];
  __shared__ float red[NH][17];
  const int j = threadIdx.x;
  #pragma unroll
  for (int p = 0; p < 16; ++p) xs[j][p] = x[(size_t)j * NPTS + n0 + p];
  __syncthreads();
  float acc[16];
  float bb = b1[j];
  #pragma unroll
  for (int p = 0; p < 16; ++p) acc[p] = bb;
  for (int c = 0; c < NC; ++c){
    float w = W1[j * NC + c];
    #pragma unroll
    for (int p = 0; p < 16; ++p) acc[p] = fmaf(w, xs[c][p], acc[p]);
  }
  float w2 = W2[j];
  #pragma unroll
  for (int p = 0; p < 16; ++p) red[j][p] = w2 * fmaxf(acc[p], 0.0f);
  __syncthreads();
  for (int s = NH / 2; s >= 1; s >>= 1){
    if (j < s){
      #pragma unroll
      for (int p = 0; p < 16; ++p) red[j][p] += red[j + s][p];
    }
    __syncthreads();
  }
  if (j < 16) out[n0 + j] = red[0][j] + b2[0];
}

// ---------------- S = feat_d^T feat_s / TEMP (fp16), plus transposed copy ----------------
#define GP 68
__global__ __launch_bounds__(256) void gemm_kernel(
    const float* __restrict__ fd, const float* __restrict__ fs,
    __half* __restrict__ S, __half* __restrict__ ST){
  const int cb = blockIdx.x, rb = blockIdx.y, b = blockIdx.z;
  const float* A = fd + (size_t)b * NC * NPTS;
  const float* Bm = fs + (size_t)b * NC * NPTS;
  __shared__ float Als[NC * GP];
  __shared__ float Bls[NC * GP];
  const int tid = threadIdx.x;
  for (int idx = tid; idx < NC * 64; idx += 256){
    int ch = idx >> 6, i = idx & 63;
    Als[ch * GP + i] = A[(size_t)ch * NPTS + rb * 64 + i];
    Bls[ch * GP + i] = Bm[(size_t)ch * NPTS + cb * 64 + i];
  }
  __syncthreads();
  const int tx = tid & 15, ty = tid >> 4;
  float acc[4][4] = {};
  for (int c = 0; c < NC; ++c){
    float4 a4 = *(const float4*)&Als[c * GP + ty * 4];
    float4 b4 = *(const float4*)&Bls[c * GP + tx * 4];
    float av[4] = {a4.x, a4.y, a4.z, a4.w};
    float bv[4] = {b4.x, b4.y, b4.z, b4.w};
    #pragma unroll
    for (int i = 0; i < 4; ++i)
      #pragma unroll
      for (int jj = 0; jj < 4; ++jj)
        acc[i][jj] = fmaf(av[i], bv[jj], acc[i][jj]);
  }
  __half* Sb = S + (size_t)b * NPTS * NPTS;
  __half* STb = ST + (size_t)b * NPTS * NPTS;
  const int r0 = rb * 64 + ty * 4, c0 = cb * 64 + tx * 4;
  #pragma unroll
  for (int i = 0; i < 4; ++i){
    __half2 p[2];
    p[0] = __float22half2_rn(make_float2(acc[i][0]*INV_TEMP, acc[i][1]*INV_TEMP));
    p[1] = __float22half2_rn(make_float2(acc[i][2]*INV_TEMP, acc[i][3]*INV_TEMP));
    *(uint2*)&Sb[(size_t)(r0 + i) * NPTS + c0] = *(uint2*)p;
  }
  #pragma unroll
  for (int jj = 0; jj < 4; ++jj){
    __half2 p[2];
    p[0] = __float22half2_rn(make_float2(acc[0][jj]*INV_TEMP, acc[1][jj]*INV_TEMP));
    p[1] = __float22half2_rn(make_float2(acc[2][jj]*INV_TEMP, acc[3][jj]*INV_TEMP));
    *(uint2*)&STb[(size_t)(c0 + jj) * NPTS + r0] = *(uint2*)p;
  }
}

// unpack 16B (8 halfs) -> 8 floats
static __device__ __forceinline__ void unpack8(uint4 raw, float* x){
  float2 f;
  f = __half22float2(*(__half2*)&raw.x); x[0]=f.x; x[1]=f.y;
  f = __half22float2(*(((__half2*)&raw.x)+1)); x[2]=f.x; x[3]=f.y;
  f = __half22float2(*(__half2*)&raw.z); x[4]=f.x; x[5]=f.y;
  f = __half22float2(*(((__half2*)&raw.z)+1)); x[6]=f.x; x[7]=f.y;
}

// ---------------- one Sinkhorn half-step: wave-per-row, shuffle-only reduction ----------------
__global__ __launch_bounds__(256) void phase_kernel(
    const __half* __restrict__ S, const __half* __restrict__ ST,
    const float* __restrict__ dust_d, const float* __restrict__ dust_s,
    float* __restrict__ u_ds, float* __restrict__ u_sd,
    float* __restrict__ v_ds, float* __restrict__ v_sd,
    const int mode){
  const int b = blockIdx.y, mat = blockIdx.z;
  const int w = threadIdx.x >> 6, lane = threadIdx.x & 63;
  const int r = blockIdx.x * 4 + w;
  const int rmax = (mode == 0) ? (NPTS + 1) : NPTS;
  if (r >= rmax) return;

  const __half* row = nullptr;
  const float* drow = nullptr;
  const float* off;
  if (mode == 0){
    if (mat == 0){
      if (r < NPTS) row = S + ((size_t)b * NPTS + r) * NPTS;
      else          drow = dust_d + (size_t)b * NPTS;
      off = v_ds + (size_t)b * NPTS;
    } else {
      if (r < NPTS) row = ST + ((size_t)b * NPTS + r) * NPTS;
      else          drow = dust_s + (size_t)b * NPTS;
      off = v_sd + (size_t)b * NPTS;
    }
  } else {
    row = (mat == 0) ? (S + ((size_t)b * NPTS + r) * NPTS)
                     : (ST + ((size_t)b * NPTS + r) * NPTS);
    off = (mat == 0) ? (u_sd + (size_t)b * (NPTS + 1))
                     : (u_ds + (size_t)b * (NPTS + 1));
  }

  float x[32];
  float ovf[32];
  #pragma unroll
  for (int k = 0; k < 8; ++k){
    const int c = (k * 64 + lane) * 4;
    float4 o = *(const float4*)&off[c];
    ovf[k*4+0]=o.x; ovf[k*4+1]=o.y; ovf[k*4+2]=o.z; ovf[k*4+3]=o.w;
  }
  if (row){
    // 4 x 16B loads = 32 fp16 elements per lane; layout matches offset layout:
    // chunk k2 covers elements (k2*64+lane)*8 .. +8
    #pragma unroll
    for (int k2 = 0; k2 < 4; ++k2){
      uint4 raw = *(const uint4*)&row[(k2 * 64 + lane) * 8];
      float xr[8];
      unpack8(raw, xr);
      // element (k2*64+lane)*8 + i  must pair with off at same index:
      // off chunk mapping: idx = (k*64+lane)*4 + i  -> k = idx/ (64*4) ... different layout!
      // So load offsets with matching layout instead below.
      #pragma unroll
      for (int i = 0; i < 8; ++i) x[k2*8+i] = xr[i];
    }
    // reload offsets with the fp16-matching layout (L1-hot, cheap)
    #pragma unroll
    for (int k2 = 0; k2 < 4; ++k2){
      const int c = (k2 * 64 + lane) * 8;
      float4 o0 = *(const float4*)&off[c];
      float4 o1 = *(const float4*)&off[c + 4];
      x[k2*8+0]+=o0.x; x[k2*8+1]+=o0.y; x[k2*8+2]+=o0.z; x[k2*8+3]+=o0.w;
      x[k2*8+4]+=o1.x; x[k2*8+5]+=o1.y; x[k2*8+6]+=o1.z; x[k2*8+7]+=o1.w;
    }
  } else {
    #pragma unroll
    for (int k = 0; k < 8; ++k){
      const int c = (k * 64 + lane) * 4;
      float4 rv = *(const float4*)&drow[c];
      x[k*4+0]=rv.x+ovf[k*4+0]; x[k*4+1]=rv.y+ovf[k*4+1];
      x[k*4+2]=rv.z+ovf[k*4+2]; x[k*4+3]=rv.w+ovf[k*4+3];
    }
  }

  float m = x[0];
  #pragma unroll
  for (int i = 1; i < 32; ++i) m = fmaxf(m, x[i]);
  float s = 0.f;
  #pragma unroll
  for (int i = 0; i < 32; ++i) s += __expf(x[i] - m);
  #pragma unroll
  for (int d = 1; d < 64; d <<= 1){
    float m2 = __shfl_xor(m, d);
    float s2 = __shfl_xor(s, d);
    lse_merge(m, s, m2, s2);
  }
  if (lane == 0){
    float lse = m + __logf(s);
    if (mode == 0){
      if (mat == 0) u_ds[(size_t)b * (NPTS + 1) + r] = -lse;
      else          u_sd[(size_t)b * (NPTS + 1) + r] = -lse;
    } else {
      float dsc, uN;
      if (mat == 0){ dsc = dust_s[(size_t)b * NPTS + r]; uN = u_sd[(size_t)b * (NPTS + 1) + NPTS]; }
      else         { dsc = dust_d[(size_t)b * NPTS + r]; uN = u_ds[(size_t)b * (NPTS + 1) + NPTS]; }
      float e = dsc + uN;
      float M2 = fmaxf(lse, e);
      lse = M2 + __logf(__expf(lse - M2) + __expf(e - M2));
      if (mat == 0) v_sd[(size_t)b * NPTS + r] = -lse;
      else          v_ds[(size_t)b * NPTS + r] = -lse;
    }
  }
}

// ---------------- final losses: wave-per-row scan over S (fp16) ----------------
__global__ __launch_bounds__(256) void loss_kernel(
    const __half* __restrict__ S,
    const float* __restrict__ u_ds, const float* __restrict__ u_sd,
    const float* __restrict__ v_ds, const float* __restrict__ v_sd,
    float* __restrict__ part){
  const int b = blockIdx.y;
  const int w = threadIdx.x >> 6, lane = threadIdx.x & 63;
  const int r = blockIdx.x * 4 + w;
  const __half* row = S + ((size_t)b * NPTS + r) * NPTS;
  const float uds = u_ds[(size_t)b * (NPTS + 1) + r];
  const float vsd = v_sd[(size_t)b * NPTS + r];
  const float* vds = v_ds + (size_t)b * NPTS;
  const float* usd = u_sd + (size_t)b * (NPTS + 1);
  float sd = 0.f, e1 = 0.f, e2 = 0.f;
  #pragma unroll
  for (int k2 = 0; k2 < 4; ++k2){
    const int c = (k2 * 64 + lane) * 8;
    uint4 raw = *(const uint4*)&row[c];
    float sv[8];
    unpack8(raw, sv);
    float4 a0 = *(const float4*)&vds[c];
    float4 a1 = *(const float4*)&vds[c + 4];
    float4 q0 = *(const float4*)&usd[c];
    float4 q1 = *(const float4*)&usd[c + 4];
    float av[8] = {a0.x,a0.y,a0.z,a0.w,a1.x,a1.y,a1.z,a1.w};
    float qv[8] = {q0.x,q0.y,q0.z,q0.w,q1.x,q1.y,q1.z,q1.w};
    #pragma unroll
    for (int i = 0; i < 8; ++i){
      float t1 = __expf(sv[i] + uds + av[i]);   // T_ds[r][c]
      float t2 = __expf(sv[i] + qv[i] + vsd);   // T_sd^T[r][c]
      float d = t1 - t2;
      sd += d * d;
      e1 += t1 * __logf(t1 + EPSF);
      e2 += t2 * __logf(t2 + EPSF);
    }
  }
  #pragma unroll
  for (int d = 1; d < 64; d <<= 1){
    sd += __shfl_xor(sd, d);
    e1 += __shfl_xor(e1, d);
    e2 += __shfl_xor(e2, d);
  }
  if (lane == 0){
    float* p = part + ((size_t)b * NPTS + r) * 4;
    p[0] = sd; p[1] = e1; p[2] = e2;
  }
}

__global__ __launch_bounds__(256) void final_kernel(const float* __restrict__ part, float* __restrict__ out){
  const int tid = threadIdx.x;
  float s0 = 0.f, s1 = 0.f, s2 = 0.f;
  for (int i = tid; i < NB * NPTS; i += 256){
    s0 += part[(size_t)i * 4 + 0];
    s1 += part[(size_t)i * 4 + 1];
    s2 += part[(size_t)i * 4 + 2];
  }
  #pragma unroll
  for (int d = 1; d < 64; d <<= 1){
    s0 += __shfl_xor(s0, d);
    s1 += __shfl_xor(s1, d);
    s2 += __shfl_xor(s2, d);
  }
  __shared__ float rs[4][3];
  const int w = tid >> 6;
  if ((tid & 63) == 0){ rs[w][0] = s0; rs[w][1] = s1; rs[w][2] = s2; }
  __syncthreads();
  if (tid == 0){
    float a0 = rs[0][0] + rs[1][0] + rs[2][0] + rs[3][0];
    float a1 = rs[0][1] + rs[1][1] + rs[2][1] + rs[3][1];
    float a2 = rs[0][2] + rs[1][2] + rs[2][2] + rs[3][2];
    float lc = a0 / (float)((size_t)NB * NPTS * NPTS);
    float le = -0.5f * (a1 + a2) / (float)NB;
    out[0] = lc + 0.01f * le;
  }
}

extern "C" void kernel_launch(void* const* d_in, const int* in_sizes, int n_in,
                              void* d_out, int out_size, void* d_ws, size_t ws_size,
                              hipStream_t stream){
  const float* fd = (const float*)d_in[0];
  const float* fs = (const float*)d_in[1];
  const float* W1 = (const float*)d_in[2];
  const float* b1 = (const float*)d_in[3];
  const float* W2 = (const float*)d_in[4];
  const float* b2 = (const float*)d_in[5];
  char* ws = (char*)d_ws;
  __half* S  = (__half*)ws;                                        // NB*NPTS*NPTS fp16
  __half* ST = S + (size_t)NB * NPTS * NPTS;                       // NB*NPTS*NPTS fp16
  float* fws = (float*)(ws + 2 * sizeof(__half) * (size_t)NB * NPTS * NPTS);
  float* dust_d = fws;
  float* dust_s = dust_d + (size_t)NB * NPTS;
  float* u_ds   = dust_s + (size_t)NB * NPTS;
  float* u_sd   = u_ds + (size_t)NB * (NPTS + 1);
  float* v_ds   = u_sd + (size_t)NB * (NPTS + 1);
  float* v_sd   = v_ds + (size_t)NB * NPTS;
  float* part   = v_sd + (size_t)NB * NPTS;

  // v_ds and v_sd are adjacent: zero both in one memset (initial potentials = 0)
  hipMemsetAsync(v_ds, 0, sizeof(float) * (size_t)NB * NPTS * 2, stream);

  dust_kernel<<<dim3(NPTS / 16, NB, 2), 128, 0, stream>>>(fd, fs, W1, b1, W2, b2, dust_d, dust_s);
  gemm_kernel<<<dim3(NPTS / 64, NPTS / 64, NB), 256, 0, stream>>>(fd, fs, S, ST);
  for (int it = 0; it < NITERS; ++it){
    phase_kernel<<<dim3((NPTS + 1 + 3) / 4, NB, 2), 256, 0, stream>>>(S, ST, dust_d, dust_s, u_ds, u_sd, v_ds, v_sd, 0);
    phase_kernel<<<dim3(NPTS / 4, NB, 2), 256, 0, stream>>>(S, ST, dust_d, dust_s, u_ds, u_sd, v_ds, v_sd, 1);
  }
  loss_kernel<<<dim3(NPTS / 4, NB), 256, 0, stream>>>(S, u_ds, u_sd, v_ds, v_sd, part);
  final_kernel<<<1, 256, 0, stream>>>(part, (float*)d_out);
}